// Round 3
// baseline (494.515 us; speedup 1.0000x reference)
//
#include <hip/hip_runtime.h>
#include <math.h>

#define B  128
#define L  64
#define NS 32
#define NI 16
#define D  256

typedef __attribute__((ext_vector_type(8))) short bf16x8;
typedef __attribute__((ext_vector_type(4))) float f32x4;

__device__ __forceinline__ float wave_reduce_sum(float v) {
#pragma unroll
  for (int off = 32; off; off >>= 1) v += __shfl_xor(v, off, 64);
  return v;
}
__device__ __forceinline__ float wave_reduce_max(float v) {
#pragma unroll
  for (int off = 32; off; off >>= 1) v = fmaxf(v, __shfl_xor(v, off, 64));
  return v;
}

// RTNE f32 -> bf16 bits
__device__ __forceinline__ ushort bf16_rtne(float f) {
  unsigned u = __float_as_uint(f);
  unsigned r = 0x7FFFu + ((u >> 16) & 1u);
  return (ushort)((u + r) >> 16);
}
// x ~= hi + lo (both bf16 RTNE); dropped cross-term ~2^-18 relative
__device__ __forceinline__ void split2(float x, ushort& hi, ushort& lo) {
  ushort h = bf16_rtne(x);
  float hf = __uint_as_float(((unsigned)h) << 16);
  hi = h;
  lo = bf16_rtne(x - hf);
}

// ---------------------------------------------------------------------------
// K1: per (b,l): a_words = mean(x); logits = w_route_ws[l] . x; softmax;
//     wlsT[l][s][b] = c_ws * a_words   (transposed layout for k3's coalesced
//     per-chunk scale preload).
// ---------------------------------------------------------------------------
__global__ __launch_bounds__(256) void k1_route_words(
    const float* __restrict__ tf, const float* __restrict__ wr,
    float* __restrict__ wlsT, float* __restrict__ a_words) {
  int bl = blockIdx.x;
  int b  = bl >> 6;
  int l  = bl & (L - 1);
  int t  = threadIdx.x;
  int wave = t >> 6, lane = t & 63;
  __shared__ float sx[D];
  __shared__ float slog[NS];
  __shared__ float s_aw;
  sx[t] = tf[bl * D + t];
  __syncthreads();
  const float* wbase = wr + l * NS * D;
#pragma unroll
  for (int r = 0; r < 8; ++r) {
    int n = wave * 8 + r;
    const float* w = wbase + n * D;
    float p = 0.f;
#pragma unroll
    for (int jj = 0; jj < 4; ++jj) {
      int j = lane + jj * 64;
      p = fmaf(w[j], sx[j], p);
    }
    p = wave_reduce_sum(p);
    if (lane == 0) slog[n] = p;
  }
  if (wave == 0) {
    float p = sx[lane] + sx[lane + 64] + sx[lane + 128] + sx[lane + 192];
    p = wave_reduce_sum(p);
    if (lane == 0) s_aw = p * (1.f / D);
  }
  __syncthreads();
  if (wave == 0) {
    float aw = s_aw;
    float v = (lane < NS) ? slog[lane] : -INFINITY;
    float m = wave_reduce_max(v);
    float e = (lane < NS) ? __expf(v - m) : 0.f;
    float s = wave_reduce_sum(e);
    if (lane < NS) wlsT[(l * NS + lane) * B + b] = (e / s) * aw;
    if (lane == 0) a_words[bl] = aw;
  }
}

// ---------------------------------------------------------------------------
// K2: weighted_c[b,s] = sum_l wlsT[l][s][b]; a_slots = wc / sum_l a_words.
// ---------------------------------------------------------------------------
__global__ __launch_bounds__(64) void k2_slots_agg(
    const float* __restrict__ wlsT, const float* __restrict__ a_words,
    float* __restrict__ weighted_c, float* __restrict__ a_slots) {
  int b = blockIdx.x;
  int lane = threadIdx.x;
  float aw = a_words[b * L + lane];
  float sa = wave_reduce_sum(aw);
  if (lane < NS) {
    float wc = 0.f;
    for (int l = 0; l < L; ++l) wc += wlsT[(l * NS + lane) * B + b];
    weighted_c[b * NS + lane] = wc;
    a_slots[b * NS + lane] = wc / sa;
  }
}

// ---------------------------------------------------------------------------
// FUSED MAIN: blocks [0, NS*NI) do the w_pose_si column-sum (old k6, pure
// HBM streaming, dispatched first); blocks [NS*NI, ...) do the split-bf16
// MFMA GEMM (old k3) with BM=128(b) x BN=64(i) x KC=32, reg-prefetch
// pipeline (T14): issue next step's global loads between stage and MFMA.
// ---------------------------------------------------------------------------
#define KP 40  // KC(32) + 8 ushort pad: 80B rows, 16B-aligned, ~2-way banks

__global__ __launch_bounds__(256) void fused_main(
    const float* __restrict__ tf, const float* __restrict__ wp,
    const float* __restrict__ wlsT, const float* __restrict__ wps,
    float* __restrict__ part, float* __restrict__ wsum, int nsplit) {
  union Smem {
    struct {
      ushort Ah[128][KP], Al[128][KP];  // A tile hi/lo (b x k)
      ushort Wh[64][KP],  Wl[64][KP];   // W tile hi/lo (i x k)
      float  sw[16][128];               // wls scales for 16 l's
    } k3;
    struct { float red[4][D]; } k6;
  };
  __shared__ Smem sm;

  int bx = blockIdx.x;
  int t  = threadIdx.x;

  if (bx < NS * NI) {
    // ---- k6 path: wsum[s,i,k] = sum_j wps[s,i,j,k] ----
    int si = bx;
    int k4 = (t & 63) * 4;
    int jg = t >> 6;
    const float* base = wps + (size_t)si * D * D;
    float4 acc = {0.f, 0.f, 0.f, 0.f};
    for (int j = jg; j < D; j += 4) {
      float4 v = *(const float4*)(base + (size_t)j * D + k4);
      acc.x += v.x; acc.y += v.y; acc.z += v.z; acc.w += v.w;
    }
    *(float4*)&sm.k6.red[jg][k4] = acc;
    __syncthreads();
    wsum[si * D + t] = (sm.k6.red[0][t] + sm.k6.red[1][t]) +
                       (sm.k6.red[2][t] + sm.k6.red[3][t]);
    return;
  }

  // ---- k3 path ----
  int kb  = bx - NS * NI;
  int sp  = kb % nsplit;
  int rem = kb / nsplit;
  int it  = rem & 3;
  int s   = rem >> 2;
  int i0  = it * 64;
  int lchunk = L / nsplit;
  int l0     = sp * lchunk;
  int tot    = lchunk * 8;  // steps: 8 jc-chunks of 32 per l

  int q8   = (t & 7) * 4;   // col quad (floats)
  int r32  = t >> 3;        // staging row base (0..31)
  int lane = t & 63;
  int wv   = t >> 6;
  int wm   = wv >> 1, wn = wv & 1;
  int fr   = lane & 15;
  int ko   = (lane >> 4) * 8;

  f32x4 acc[4][2];
#pragma unroll
  for (int mi = 0; mi < 4; ++mi)
#pragma unroll
    for (int ni = 0; ni < 2; ++ni) acc[mi][ni] = (f32x4)0.f;

  float4 rA[4], rW[2];
  auto load_step = [&](int step) {
    if (step >= tot) step = tot - 1;
    int l  = l0 + (step >> 3);
    int jc = (step & 7) * 32;
#pragma unroll
    for (int p = 0; p < 4; ++p)
      rA[p] = *(const float4*)(tf + ((size_t)(r32 + 32 * p) * L + l) * D + jc + q8);
    const float* wbase = wp + ((size_t)l * NS + s) * (D * D) + jc + q8;
#pragma unroll
    for (int p = 0; p < 2; ++p)
      rW[p] = *(const float4*)(wbase + (size_t)(i0 + r32 + 32 * p) * D);
  };

  load_step(0);

  for (int lc = 0; lc < lchunk; lc += 16) {
    // preload wls scales for the next 16 l's (coalesced from wlsT[l][s][b])
    for (int ofs = t; ofs < 16 * 128; ofs += 256) {
      int li = ofs >> 7, b = ofs & 127;
      sm.k3.sw[li][b] = wlsT[((size_t)(l0 + lc + li) * NS + s) * B + b];
    }
    __syncthreads();
    int nst = (lchunk - lc < 16 ? lchunk - lc : 16) * 8;
    for (int st = 0; st < nst; ++st) {
      int step = lc * 8 + st;
      int li   = (step >> 3) - lc;
      // stage current regs -> LDS (split to hi/lo bf16)
#pragma unroll
      for (int p = 0; p < 4; ++p) {
        int row = r32 + 32 * p;
        float sc = sm.k3.sw[li][row];
        ushort4 h4, l4;
        split2(rA[p].x * sc, h4.x, l4.x);
        split2(rA[p].y * sc, h4.y, l4.y);
        split2(rA[p].z * sc, h4.z, l4.z);
        split2(rA[p].w * sc, h4.w, l4.w);
        *(ushort4*)&sm.k3.Ah[row][q8] = h4;
        *(ushort4*)&sm.k3.Al[row][q8] = l4;
      }
#pragma unroll
      for (int p = 0; p < 2; ++p) {
        int row = r32 + 32 * p;
        ushort4 h4, l4;
        split2(rW[p].x, h4.x, l4.x);
        split2(rW[p].y, h4.y, l4.y);
        split2(rW[p].z, h4.z, l4.z);
        split2(rW[p].w, h4.w, l4.w);
        *(ushort4*)&sm.k3.Wh[row][q8] = h4;
        *(ushort4*)&sm.k3.Wl[row][q8] = l4;
      }
      // prefetch next step (HBM latency hides under barrier + MFMA)
      load_step(step + 1);
      __syncthreads();
      // MFMA: 3-term emulated-fp32, one K=32 step
      bf16x8 bh0 = *(const bf16x8*)&sm.k3.Wh[wn * 32 + fr][ko];
      bf16x8 bl0 = *(const bf16x8*)&sm.k3.Wl[wn * 32 + fr][ko];
      bf16x8 bh1 = *(const bf16x8*)&sm.k3.Wh[wn * 32 + 16 + fr][ko];
      bf16x8 bl1 = *(const bf16x8*)&sm.k3.Wl[wn * 32 + 16 + fr][ko];
#pragma unroll
      for (int mi = 0; mi < 4; ++mi) {
        bf16x8 ah = *(const bf16x8*)&sm.k3.Ah[wm * 64 + mi * 16 + fr][ko];
        bf16x8 al = *(const bf16x8*)&sm.k3.Al[wm * 64 + mi * 16 + fr][ko];
        acc[mi][0] = __builtin_amdgcn_mfma_f32_16x16x32_bf16(ah, bh0, acc[mi][0], 0, 0, 0);
        acc[mi][0] = __builtin_amdgcn_mfma_f32_16x16x32_bf16(ah, bl0, acc[mi][0], 0, 0, 0);
        acc[mi][0] = __builtin_amdgcn_mfma_f32_16x16x32_bf16(al, bh0, acc[mi][0], 0, 0, 0);
        acc[mi][1] = __builtin_amdgcn_mfma_f32_16x16x32_bf16(ah, bh1, acc[mi][1], 0, 0, 0);
        acc[mi][1] = __builtin_amdgcn_mfma_f32_16x16x32_bf16(ah, bl1, acc[mi][1], 0, 0, 0);
        acc[mi][1] = __builtin_amdgcn_mfma_f32_16x16x32_bf16(al, bh1, acc[mi][1], 0, 0, 0);
      }
      __syncthreads();  // MFMA readers done before next stage overwrites
    }
  }

  // epilogue: write partials
  float* pout = part + ((size_t)sp * NS + s) * (B * D);
#pragma unroll
  for (int mi = 0; mi < 4; ++mi)
#pragma unroll
    for (int ni = 0; ni < 2; ++ni) {
      int col = i0 + wn * 32 + ni * 16 + fr;
#pragma unroll
      for (int r = 0; r < 4; ++r) {
        int bb = wm * 64 + mi * 16 + (lane >> 4) * 4 + r;
        pout[(size_t)bb * D + col] = acc[mi][ni][r];
      }
    }
}

// ---------------------------------------------------------------------------
// K3R: u_slots[b,s,i] = (sum_sp part[sp,s,b,i]) / weighted_c[b,s]
// ---------------------------------------------------------------------------
__global__ __launch_bounds__(256) void k3r_reduce(
    const float* __restrict__ part, const float* __restrict__ wc,
    float* __restrict__ u_slots, int nsplit) {
  int idx = blockIdx.x * 256 + threadIdx.x;  // over (s,b,i)
  int i  = idx & (D - 1);
  int sb = idx >> 8;
  int b  = sb & (B - 1);
  int s  = sb >> 7;
  float v = 0.f;
  for (int sp = 0; sp < nsplit; ++sp)
    v += part[(size_t)sp * (NS * B * D) + idx];
  u_slots[((size_t)b * NS + s) * D + i] = v / wc[b * NS + s];
}

// ---------------------------------------------------------------------------
// K4: per (b,s): logits2 = w_route_si[s] . u_slots[b,s]; softmax over NI;
//     w2 = c_si * a_slots.
// ---------------------------------------------------------------------------
__global__ __launch_bounds__(64) void k4_route_si(
    const float* __restrict__ u_slots, const float* __restrict__ wr_si,
    const float* __restrict__ a_slots, float* __restrict__ w2) {
  int bs = blockIdx.x;
  int s  = bs & (NS - 1);
  int lane = threadIdx.x;
  __shared__ float su[D];
  __shared__ float slog[NI];
#pragma unroll
  for (int jj = 0; jj < 4; ++jj) su[lane + jj * 64] = u_slots[bs * D + lane + jj * 64];
  __syncthreads();
  for (int i = 0; i < NI; ++i) {
    const float* w = wr_si + (s * NI + i) * D;
    float p = 0.f;
#pragma unroll
    for (int jj = 0; jj < 4; ++jj) {
      int j = lane + jj * 64;
      p = fmaf(w[j], su[j], p);
    }
    p = wave_reduce_sum(p);
    if (lane == 0) slog[i] = p;
  }
  __syncthreads();
  float v = (lane < NI) ? slog[lane] : -INFINITY;
  float m = wave_reduce_max(v);
  float e = (lane < NI) ? __expf(v - m) : 0.f;
  float ssum = wave_reduce_sum(e);
  if (lane < NI) w2[bs * NI + lane] = (e / ssum) * a_slots[bs];
}

// ---------------------------------------------------------------------------
// K5: wc2[b,i] = sum_s w2; a_intents = wc2 / sum_s a_slots.
// ---------------------------------------------------------------------------
__global__ __launch_bounds__(64) void k5_intents_agg(
    const float* __restrict__ w2, const float* __restrict__ a_slots,
    float* __restrict__ wc2, float* __restrict__ a_intents) {
  int b = blockIdx.x;
  int lane = threadIdx.x;
  float as = (lane < NS) ? a_slots[b * NS + lane] : 0.f;
  float sas = wave_reduce_sum(as);
  if (lane < NI) {
    float wc = 0.f;
    for (int s = 0; s < NS; ++s) wc += w2[(b * NS + s) * NI + lane];
    wc2[b * NI + lane] = wc;
    a_intents[b * NI + lane] = wc / sas;
  }
}

// ---------------------------------------------------------------------------
// K7: u_intents[b,i,k] = sum_s w2[b,s,i]*u_slots[b,s,k]*Wsum[s,i,k] / wc2[b,i]
// ---------------------------------------------------------------------------
__global__ __launch_bounds__(256) void k7_uintents(
    const float* __restrict__ u_slots, const float* __restrict__ w2,
    const float* __restrict__ wsum, const float* __restrict__ wc2,
    float* __restrict__ u_intents) {
  int bi = blockIdx.x;
  int b = bi >> 4, i = bi & (NI - 1);
  int k = threadIdx.x;
  float acc = 0.f;
  for (int s = 0; s < NS; ++s) {
    float w = w2[(b * NS + s) * NI + i];
    acc = fmaf(w * u_slots[(b * NS + s) * D + k], wsum[(s * NI + i) * D + k], acc);
  }
  u_intents[bi * D + k] = acc / wc2[bi];
}

// ---------------------------------------------------------------------------
extern "C" void kernel_launch(void* const* d_in, const int* in_sizes, int n_in,
                              void* d_out, int out_size, void* d_ws, size_t ws_size,
                              hipStream_t stream) {
  const float* tf    = (const float*)d_in[0];  // (B,L,D)
  const float* wr_ws = (const float*)d_in[1];  // (L,NS,D)
  const float* wp_ws = (const float*)d_in[2];  // (L,NS,D,D)
  const float* wr_si = (const float*)d_in[3];  // (NS,NI,D)
  const float* wp_si = (const float*)d_in[4];  // (NS,NI,D,D)

  float* out       = (float*)d_out;
  float* a_slots   = out;                      // B*NS
  float* u_slots   = a_slots + B * NS;         // B*NS*D
  float* a_intents = u_slots + B * NS * D;     // B*NI
  float* u_intents = a_intents + B * NI;       // B*NI*D

  float* ws         = (float*)d_ws;
  float* wlsT       = ws;                      // L*NS*B  = 262144
  float* a_words    = wlsT + L * NS * B;       // B*L     = 8192
  float* weighted_c = a_words + B * L;         // B*NS    = 4096
  float* w2         = weighted_c + B * NS;     // B*NS*NI = 65536
  float* wc2        = w2 + B * NS * NI;        // B*NI    = 2048
  float* wsum       = wc2 + B * NI;            // NS*NI*D = 131072
  float* part       = wsum + NS * NI * D;      // nsplit * NS*B*D

  const size_t base_f  = 473088;
  const size_t chunk_f = (size_t)NS * B * D;   // 1,048,576 floats per split
  size_t avail_f = ws_size / sizeof(float);
  int nsplit = 1;
  if (avail_f >= base_f + 4 * chunk_f)      nsplit = 4;
  else if (avail_f >= base_f + 2 * chunk_f) nsplit = 2;

  k1_route_words<<<B * L, 256, 0, stream>>>(tf, wr_ws, wlsT, a_words);
  k2_slots_agg<<<B, 64, 0, stream>>>(wlsT, a_words, weighted_c, a_slots);
  fused_main<<<NS * NI + NS * 4 * nsplit, 256, 0, stream>>>(
      tf, wp_ws, wlsT, wp_si, part, wsum, nsplit);
  k3r_reduce<<<(NS * B * D) / 256, 256, 0, stream>>>(part, weighted_c, u_slots, nsplit);
  k4_route_si<<<B * NS, 64, 0, stream>>>(u_slots, wr_si, a_slots, w2);
  k5_intents_agg<<<B, 64, 0, stream>>>(w2, a_slots, wc2, a_intents);
  k7_uintents<<<B * NI, 256, 0, stream>>>(u_slots, w2, wsum, wc2, u_intents);
}

// Round 4
// 432.307 us; speedup vs baseline: 1.1439x; 1.1439x over previous
//
#include <hip/hip_runtime.h>
#include <math.h>

#define B  128
#define L  64
#define NS 32
#define NI 16
#define D  256

typedef __attribute__((ext_vector_type(8))) short bf16x8;
typedef __attribute__((ext_vector_type(4))) float f32x4;

__device__ __forceinline__ float wave_reduce_sum(float v) {
#pragma unroll
  for (int off = 32; off; off >>= 1) v += __shfl_xor(v, off, 64);
  return v;
}
__device__ __forceinline__ float wave_reduce_max(float v) {
#pragma unroll
  for (int off = 32; off; off >>= 1) v = fmaxf(v, __shfl_xor(v, off, 64));
  return v;
}

// RTNE f32 -> bf16 bits
__device__ __forceinline__ ushort bf16_rtne(float f) {
  unsigned u = __float_as_uint(f);
  unsigned r = 0x7FFFu + ((u >> 16) & 1u);
  return (ushort)((u + r) >> 16);
}
// x ~= hi + lo (both bf16 RTNE); dropped cross-term ~2^-18 relative
__device__ __forceinline__ void split2(float x, ushort& hi, ushort& lo) {
  ushort h = bf16_rtne(x);
  float hf = __uint_as_float(((unsigned)h) << 16);
  hi = h;
  lo = bf16_rtne(x - hf);
}

// barrier that does NOT drain vmcnt (keeps prefetch loads in flight)
#define LGKM_BARRIER()                                   \
  do {                                                   \
    asm volatile("s_waitcnt lgkmcnt(0)" ::: "memory");   \
    __builtin_amdgcn_s_barrier();                        \
    asm volatile("" ::: "memory");                       \
  } while (0)

// ---------------------------------------------------------------------------
// K1: per (b,l): a_words = mean(x); logits = w_route_ws[l] . x; softmax;
//     wlsT[l][s][b] = c_ws * a_words.
// ---------------------------------------------------------------------------
__global__ __launch_bounds__(256) void k1_route_words(
    const float* __restrict__ tf, const float* __restrict__ wr,
    float* __restrict__ wlsT, float* __restrict__ a_words) {
  int bl = blockIdx.x;
  int b  = bl >> 6;
  int l  = bl & (L - 1);
  int t  = threadIdx.x;
  int wave = t >> 6, lane = t & 63;
  __shared__ float sx[D];
  __shared__ float slog[NS];
  __shared__ float s_aw;
  sx[t] = tf[bl * D + t];
  __syncthreads();
  const float* wbase = wr + l * NS * D;
#pragma unroll
  for (int r = 0; r < 8; ++r) {
    int n = wave * 8 + r;
    const float* w = wbase + n * D;
    float p = 0.f;
#pragma unroll
    for (int jj = 0; jj < 4; ++jj) {
      int j = lane + jj * 64;
      p = fmaf(w[j], sx[j], p);
    }
    p = wave_reduce_sum(p);
    if (lane == 0) slog[n] = p;
  }
  if (wave == 0) {
    float p = sx[lane] + sx[lane + 64] + sx[lane + 128] + sx[lane + 192];
    p = wave_reduce_sum(p);
    if (lane == 0) s_aw = p * (1.f / D);
  }
  __syncthreads();
  if (wave == 0) {
    float aw = s_aw;
    float v = (lane < NS) ? slog[lane] : -INFINITY;
    float m = wave_reduce_max(v);
    float e = (lane < NS) ? __expf(v - m) : 0.f;
    float s = wave_reduce_sum(e);
    if (lane < NS) wlsT[(l * NS + lane) * B + b] = (e / s) * aw;
    if (lane == 0) a_words[bl] = aw;
  }
}

// ---------------------------------------------------------------------------
// K2: weighted_c[b,s] = sum_l wlsT[l][s][b]; a_slots = wc / sum_l a_words.
// ---------------------------------------------------------------------------
__global__ __launch_bounds__(64) void k2_slots_agg(
    const float* __restrict__ wlsT, const float* __restrict__ a_words,
    float* __restrict__ weighted_c, float* __restrict__ a_slots) {
  int b = blockIdx.x;
  int lane = threadIdx.x;
  float aw = a_words[b * L + lane];
  float sa = wave_reduce_sum(aw);
  if (lane < NS) {
    float wc = 0.f;
    for (int l = 0; l < L; ++l) wc += wlsT[(l * NS + lane) * B + b];
    weighted_c[b * NS + lane] = wc;
    a_slots[b * NS + lane] = wc / sa;
  }
}

// ---------------------------------------------------------------------------
// FUSED MAIN. k6 role (w_pose_si column-sum, pure streaming) interleaved with
// k3 role (split-bf16 MFMA GEMM, round-2 structure + T14 reg prefetch +
// lgkm-only barriers so prefetch loads stay in flight across barriers).
// k3: BM=128(b) x BN=128(i) x KC=64, 4 waves, each a 64x64 quadrant,
//     3-term emulated-fp32 (Ah*Bh + Ah*Bl + Al*Bh).
// ---------------------------------------------------------------------------
#define KP 72  // 64 + 8 ushort pad: 144B row stride (proven conflict-clean)

__global__ __launch_bounds__(256, 2) void fused_main(
    const float* __restrict__ tf, const float* __restrict__ wp,
    const float* __restrict__ wlsT, const float* __restrict__ wps,
    float* __restrict__ part, float* __restrict__ wsum,
    int nsplit, int nk3) {
  union Smem {
    struct { ushort Ah[128][KP], Al[128][KP], Wh[128][KP], Wl[128][KP]; } k3;
    struct { float red[4][D]; } k6;
  };
  __shared__ Smem sm;

  int bx = blockIdx.x;
  int t  = threadIdx.x;

  bool isK6;
  int idx;
  if (nk3 == 512) {          // interleaved: odd = k6, even = k3
    isK6 = (bx & 1);
    idx  = bx >> 1;
  } else {                   // fallback: k6 first
    isK6 = bx < NS * NI;
    idx  = isK6 ? bx : bx - NS * NI;
  }

  if (isK6) {
    // ---- k6: wsum[s,i,k] = sum_j wps[s,i,j,k] ----
    int si = idx;
    int k4 = (t & 63) * 4;
    int jg = t >> 6;
    const float* base = wps + (size_t)si * D * D;
    float4 acc = {0.f, 0.f, 0.f, 0.f};
    for (int j = jg; j < D; j += 4) {
      float4 v = *(const float4*)(base + (size_t)j * D + k4);
      acc.x += v.x; acc.y += v.y; acc.z += v.z; acc.w += v.w;
    }
    *(float4*)&sm.k6.red[jg][k4] = acc;
    __syncthreads();
    wsum[si * D + t] = (sm.k6.red[0][t] + sm.k6.red[1][t]) +
                       (sm.k6.red[2][t] + sm.k6.red[3][t]);
    return;
  }

  // ---- k3 path ----
  int sp  = idx % nsplit;
  int rem = idx / nsplit;
  int it  = rem & 1;
  int s   = rem >> 1;
  int i0  = it * 128;
  int lchunk = L / nsplit;
  int l0     = sp * lchunk;
  int steps  = lchunk * 4;  // 4 jc-chunks of 64 per l

  int rb   = t >> 4;        // staging row base (0..15)
  int jq   = (t & 15) * 4;  // col quad within KC
  int lane = t & 63;
  int wv   = t >> 6;
  int wm   = wv >> 1, wn = wv & 1;
  int fr   = lane & 15;
  int ko   = (lane >> 4) * 8;

  f32x4 acc[4][4];
#pragma unroll
  for (int mi = 0; mi < 4; ++mi)
#pragma unroll
    for (int ni = 0; ni < 4; ++ni) acc[mi][ni] = (f32x4)0.f;

  float4 rA[8], rW[8];
  float  swr[8];
  auto load_step = [&](int step) {
    if (step >= steps) step = steps - 1;
    int l  = l0 + (step >> 2);
    int jc = (step & 3) * 64;
    const float* abase = tf + (size_t)l * D + jc + jq;
    const float* sbase = wlsT + ((size_t)l * NS + s) * B;
    const float* wbase = wp + ((size_t)l * NS + s) * (D * D) + (size_t)i0 * D + jc + jq;
#pragma unroll
    for (int p = 0; p < 8; ++p) {
      int bb = p * 16 + rb;
      rA[p]  = *(const float4*)(abase + (size_t)bb * (L * D));
      swr[p] = sbase[bb];
      rW[p]  = *(const float4*)(wbase + (size_t)bb * D);
    }
  };

  load_step(0);

  for (int step = 0; step < steps; ++step) {
    // ---- stage current regs -> LDS (scale A, split hi/lo) ----
#pragma unroll
    for (int p = 0; p < 8; ++p) {
      int bb = p * 16 + rb;
      float sc = swr[p];
      ushort4 h4, l4;
      split2(rA[p].x * sc, h4.x, l4.x);
      split2(rA[p].y * sc, h4.y, l4.y);
      split2(rA[p].z * sc, h4.z, l4.z);
      split2(rA[p].w * sc, h4.w, l4.w);
      *(ushort4*)&sm.k3.Ah[bb][jq] = h4;
      *(ushort4*)&sm.k3.Al[bb][jq] = l4;
      ushort4 wh4, wl4;
      split2(rW[p].x, wh4.x, wl4.x);
      split2(rW[p].y, wh4.y, wl4.y);
      split2(rW[p].z, wh4.z, wl4.z);
      split2(rW[p].w, wh4.w, wl4.w);
      *(ushort4*)&sm.k3.Wh[bb][jq] = wh4;
      *(ushort4*)&sm.k3.Wl[bb][jq] = wl4;
    }
    // ---- prefetch next step's global data (stays in flight across barrier)
    load_step(step + 1);
    LGKM_BARRIER();  // staging visible; vmcnt NOT drained
    // ---- MFMA: 3-term emulated fp32, KC=64 ----
#pragma unroll
    for (int k32 = 0; k32 < 2; ++k32) {
      int kb = k32 * 32 + ko;
      bf16x8 ah[4], al[4], bh[4], bl[4];
#pragma unroll
      for (int mi = 0; mi < 4; ++mi) {
        ah[mi] = *(const bf16x8*)&sm.k3.Ah[wm * 64 + mi * 16 + fr][kb];
        al[mi] = *(const bf16x8*)&sm.k3.Al[wm * 64 + mi * 16 + fr][kb];
      }
#pragma unroll
      for (int ni = 0; ni < 4; ++ni) {
        bh[ni] = *(const bf16x8*)&sm.k3.Wh[wn * 64 + ni * 16 + fr][kb];
        bl[ni] = *(const bf16x8*)&sm.k3.Wl[wn * 64 + ni * 16 + fr][kb];
      }
#pragma unroll
      for (int mi = 0; mi < 4; ++mi)
#pragma unroll
        for (int ni = 0; ni < 4; ++ni) {
          acc[mi][ni] = __builtin_amdgcn_mfma_f32_16x16x32_bf16(ah[mi], bh[ni], acc[mi][ni], 0, 0, 0);
          acc[mi][ni] = __builtin_amdgcn_mfma_f32_16x16x32_bf16(ah[mi], bl[ni], acc[mi][ni], 0, 0, 0);
          acc[mi][ni] = __builtin_amdgcn_mfma_f32_16x16x32_bf16(al[mi], bh[ni], acc[mi][ni], 0, 0, 0);
        }
    }
    LGKM_BARRIER();  // all reads done before next stage overwrites
  }

  // ---- epilogue: write partials ----
  float* pout = part + ((size_t)sp * NS + s) * (B * D) + i0;
#pragma unroll
  for (int mi = 0; mi < 4; ++mi)
#pragma unroll
    for (int ni = 0; ni < 4; ++ni) {
      int col = wn * 64 + ni * 16 + fr;
#pragma unroll
      for (int r = 0; r < 4; ++r) {
        int bb = wm * 64 + mi * 16 + (lane >> 4) * 4 + r;
        pout[(size_t)bb * D + col] = acc[mi][ni][r];
      }
    }
}

// ---------------------------------------------------------------------------
// K3R: u_slots[b,s,i] = (sum_sp part[sp,s,b,i]) / weighted_c[b,s]
// ---------------------------------------------------------------------------
__global__ __launch_bounds__(256) void k3r_reduce(
    const float* __restrict__ part, const float* __restrict__ wc,
    float* __restrict__ u_slots, int nsplit) {
  int idx = blockIdx.x * 256 + threadIdx.x;  // over (s,b,i)
  int i  = idx & (D - 1);
  int sb = idx >> 8;
  int b  = sb & (B - 1);
  int s  = sb >> 7;
  float v = 0.f;
  for (int sp = 0; sp < nsplit; ++sp)
    v += part[(size_t)sp * (NS * B * D) + idx];
  u_slots[((size_t)b * NS + s) * D + i] = v / wc[b * NS + s];
}

// ---------------------------------------------------------------------------
// K4: per (b,s): logits2 = w_route_si[s] . u_slots[b,s]; softmax over NI;
//     w2 = c_si * a_slots.
// ---------------------------------------------------------------------------
__global__ __launch_bounds__(64) void k4_route_si(
    const float* __restrict__ u_slots, const float* __restrict__ wr_si,
    const float* __restrict__ a_slots, float* __restrict__ w2) {
  int bs = blockIdx.x;
  int s  = bs & (NS - 1);
  int lane = threadIdx.x;
  __shared__ float su[D];
  __shared__ float slog[NI];
#pragma unroll
  for (int jj = 0; jj < 4; ++jj) su[lane + jj * 64] = u_slots[bs * D + lane + jj * 64];
  __syncthreads();
  for (int i = 0; i < NI; ++i) {
    const float* w = wr_si + (s * NI + i) * D;
    float p = 0.f;
#pragma unroll
    for (int jj = 0; jj < 4; ++jj) {
      int j = lane + jj * 64;
      p = fmaf(w[j], su[j], p);
    }
    p = wave_reduce_sum(p);
    if (lane == 0) slog[i] = p;
  }
  __syncthreads();
  float v = (lane < NI) ? slog[lane] : -INFINITY;
  float m = wave_reduce_max(v);
  float e = (lane < NI) ? __expf(v - m) : 0.f;
  float ssum = wave_reduce_sum(e);
  if (lane < NI) w2[bs * NI + lane] = (e / ssum) * a_slots[bs];
}

// ---------------------------------------------------------------------------
// K5: wc2[b,i] = sum_s w2; a_intents = wc2 / sum_s a_slots.
// ---------------------------------------------------------------------------
__global__ __launch_bounds__(64) void k5_intents_agg(
    const float* __restrict__ w2, const float* __restrict__ a_slots,
    float* __restrict__ wc2, float* __restrict__ a_intents) {
  int b = blockIdx.x;
  int lane = threadIdx.x;
  float as = (lane < NS) ? a_slots[b * NS + lane] : 0.f;
  float sas = wave_reduce_sum(as);
  if (lane < NI) {
    float wc = 0.f;
    for (int s = 0; s < NS; ++s) wc += w2[(b * NS + s) * NI + lane];
    wc2[b * NI + lane] = wc;
    a_intents[b * NI + lane] = wc / sas;
  }
}

// ---------------------------------------------------------------------------
// K7: u_intents[b,i,k] = sum_s w2[b,s,i]*u_slots[b,s,k]*Wsum[s,i,k] / wc2[b,i]
// ---------------------------------------------------------------------------
__global__ __launch_bounds__(256) void k7_uintents(
    const float* __restrict__ u_slots, const float* __restrict__ w2,
    const float* __restrict__ wsum, const float* __restrict__ wc2,
    float* __restrict__ u_intents) {
  int bi = blockIdx.x;
  int b = bi >> 4, i = bi & (NI - 1);
  int k = threadIdx.x;
  float acc = 0.f;
  for (int s = 0; s < NS; ++s) {
    float w = w2[(b * NS + s) * NI + i];
    acc = fmaf(w * u_slots[(b * NS + s) * D + k], wsum[(s * NI + i) * D + k], acc);
  }
  u_intents[bi * D + k] = acc / wc2[bi];
}

// ---------------------------------------------------------------------------
extern "C" void kernel_launch(void* const* d_in, const int* in_sizes, int n_in,
                              void* d_out, int out_size, void* d_ws, size_t ws_size,
                              hipStream_t stream) {
  const float* tf    = (const float*)d_in[0];  // (B,L,D)
  const float* wr_ws = (const float*)d_in[1];  // (L,NS,D)
  const float* wp_ws = (const float*)d_in[2];  // (L,NS,D,D)
  const float* wr_si = (const float*)d_in[3];  // (NS,NI,D)
  const float* wp_si = (const float*)d_in[4];  // (NS,NI,D,D)

  float* out       = (float*)d_out;
  float* a_slots   = out;                      // B*NS
  float* u_slots   = a_slots + B * NS;         // B*NS*D
  float* a_intents = u_slots + B * NS * D;     // B*NI
  float* u_intents = a_intents + B * NI;       // B*NI*D

  float* ws         = (float*)d_ws;
  float* wlsT       = ws;                      // L*NS*B  = 262144
  float* a_words    = wlsT + L * NS * B;       // B*L     = 8192
  float* weighted_c = a_words + B * L;         // B*NS    = 4096
  float* w2         = weighted_c + B * NS;     // B*NS*NI = 65536
  float* wc2        = w2 + B * NS * NI;        // B*NI    = 2048
  float* wsum       = wc2 + B * NI;            // NS*NI*D = 131072
  float* part       = wsum + NS * NI * D;      // nsplit * NS*B*D

  const size_t base_f  = 473088;
  const size_t chunk_f = (size_t)NS * B * D;   // 1,048,576 floats per split
  size_t avail_f = ws_size / sizeof(float);
  int nsplit = 1;
  if (avail_f >= base_f + 8 * chunk_f)      nsplit = 8;
  else if (avail_f >= base_f + 4 * chunk_f) nsplit = 4;
  else if (avail_f >= base_f + 2 * chunk_f) nsplit = 2;

  int nk3  = 64 * nsplit;        // k3 blocks: 32 s x 2 i-tiles x nsplit
  int grid = nk3 + NS * NI;      // + 512 k6 blocks

  k1_route_words<<<B * L, 256, 0, stream>>>(tf, wr_ws, wlsT, a_words);
  k2_slots_agg<<<B, 64, 0, stream>>>(wlsT, a_words, weighted_c, a_slots);
  fused_main<<<grid, 256, 0, stream>>>(tf, wp_ws, wlsT, wp_si, part, wsum,
                                       nsplit, nk3);
  k3r_reduce<<<(NS * B * D) / 256, 256, 0, stream>>>(part, weighted_c, u_slots, nsplit);
  k4_route_si<<<B * NS, 64, 0, stream>>>(u_slots, wr_si, a_slots, w2);
  k5_intents_agg<<<B, 64, 0, stream>>>(w2, a_slots, wc2, a_intents);
  k7_uintents<<<B * NI, 256, 0, stream>>>(u_slots, w2, wsum, wc2, u_intents);
}

// Round 5
// 277.558 us; speedup vs baseline: 1.7817x; 1.5575x over previous
//
#include <hip/hip_runtime.h>
#include <math.h>

#define B  128
#define L  64
#define NS 32
#define NI 16
#define D  256

typedef __attribute__((ext_vector_type(8))) short bf16x8;
typedef __attribute__((ext_vector_type(4))) float f32x4;

__device__ __forceinline__ float wave_reduce_sum(float v) {
#pragma unroll
  for (int off = 32; off; off >>= 1) v += __shfl_xor(v, off, 64);
  return v;
}
__device__ __forceinline__ float wave_reduce_max(float v) {
#pragma unroll
  for (int off = 32; off; off >>= 1) v = fmaxf(v, __shfl_xor(v, off, 64));
  return v;
}

// packed RTNE f32x2 -> bf16x2 (single HW instr)
__device__ __forceinline__ uint cvt_pk_bf16(float a, float b) {
  uint r;
  asm("v_cvt_pk_bf16_f32 %0, %1, %2" : "=v"(r) : "v"(a), "v"(b));
  return r;  // lo16 = bf16(a), hi16 = bf16(b)
}
// float4 -> hi-pair u32x2 + lo-pair u32x2 (x ~= hi + lo, residual ~2^-17)
__device__ __forceinline__ void split4(float4 v, uint2& h, uint2& lo) {
  h.x = cvt_pk_bf16(v.x, v.y);
  h.y = cvt_pk_bf16(v.z, v.w);
  float h0 = __uint_as_float(h.x << 16);
  float h1 = __uint_as_float(h.x & 0xFFFF0000u);
  float h2 = __uint_as_float(h.y << 16);
  float h3 = __uint_as_float(h.y & 0xFFFF0000u);
  lo.x = cvt_pk_bf16(v.x - h0, v.y - h1);
  lo.y = cvt_pk_bf16(v.z - h2, v.w - h3);
}

// barrier that does NOT drain vmcnt (prefetch loads stay in flight)
#define LGKM_BARRIER()                                   \
  do {                                                   \
    asm volatile("s_waitcnt lgkmcnt(0)" ::: "memory");   \
    __builtin_amdgcn_s_barrier();                        \
    asm volatile("" ::: "memory");                       \
  } while (0)

// swizzled ushort index into a [128 rows][64 cols] bf16 LDS tile, 128B rows.
// XOR of (row&7)<<4 into the byte offset: write (ushort4) and read (b128)
// patterns both become bank-uniform.
__device__ __forceinline__ int swzA(int row, int kcol) {
  int byte = (row << 7) + (kcol << 1);
  byte ^= (row & 7) << 4;
  return byte >> 1;
}

// ---------------------------------------------------------------------------
// K1: per (b,l): a_words = mean(x); logits = w_route_ws[l] . x; softmax;
//     wlsT[l][s][b] = c_ws * a_words.
// ---------------------------------------------------------------------------
__global__ __launch_bounds__(256) void k1_route_words(
    const float* __restrict__ tf, const float* __restrict__ wr,
    float* __restrict__ wlsT, float* __restrict__ a_words) {
  int bl = blockIdx.x;
  int b  = bl >> 6;
  int l  = bl & (L - 1);
  int t  = threadIdx.x;
  int wave = t >> 6, lane = t & 63;
  __shared__ float sx[D];
  __shared__ float slog[NS];
  __shared__ float s_aw;
  sx[t] = tf[bl * D + t];
  __syncthreads();
  const float* wbase = wr + l * NS * D;
#pragma unroll
  for (int r = 0; r < 8; ++r) {
    int n = wave * 8 + r;
    const float* w = wbase + n * D;
    float p = 0.f;
#pragma unroll
    for (int jj = 0; jj < 4; ++jj) {
      int j = lane + jj * 64;
      p = fmaf(w[j], sx[j], p);
    }
    p = wave_reduce_sum(p);
    if (lane == 0) slog[n] = p;
  }
  if (wave == 0) {
    float p = sx[lane] + sx[lane + 64] + sx[lane + 128] + sx[lane + 192];
    p = wave_reduce_sum(p);
    if (lane == 0) s_aw = p * (1.f / D);
  }
  __syncthreads();
  if (wave == 0) {
    float aw = s_aw;
    float v = (lane < NS) ? slog[lane] : -INFINITY;
    float m = wave_reduce_max(v);
    float e = (lane < NS) ? __expf(v - m) : 0.f;
    float s = wave_reduce_sum(e);
    if (lane < NS) wlsT[(l * NS + lane) * B + b] = (e / s) * aw;
    if (lane == 0) a_words[bl] = aw;
  }
}

// ---------------------------------------------------------------------------
// K2: weighted_c[b,s] = sum_l wlsT[l][s][b]; a_slots = wc / sum_l a_words.
// ---------------------------------------------------------------------------
__global__ __launch_bounds__(64) void k2_slots_agg(
    const float* __restrict__ wlsT, const float* __restrict__ a_words,
    float* __restrict__ weighted_c, float* __restrict__ a_slots) {
  int b = blockIdx.x;
  int lane = threadIdx.x;
  float aw = a_words[b * L + lane];
  float sa = wave_reduce_sum(aw);
  if (lane < NS) {
    float wc = 0.f;
    for (int l = 0; l < L; ++l) wc += wlsT[(l * NS + lane) * B + b];
    weighted_c[b * NS + lane] = wc;
    a_slots[b * NS + lane] = wc / sa;
  }
}

// ---------------------------------------------------------------------------
// K3 v3: split-bf16 MFMA GEMM, W direct global->reg (no LDS), A in 32KB
// swizzled LDS.  Per block (s, i-tile of 64, l-chunk):
//   part[sp,s,b,i] = sum_{l,j} Wp[l,s,i,j] * (wls[b,l,s]*x[b,l,j])
// 256 thr / 4 waves; wave wn owns i-cols [i0+wn*16, +16); acc[8] covers all
// 128 b-rows.  3-term emulated fp32: Ah*Bh + Ah*Bl + Al*Bh.
// ---------------------------------------------------------------------------
__global__ __launch_bounds__(256, 4) void k3_mfma(
    const float* __restrict__ tf, const float* __restrict__ wp,
    const float* __restrict__ wlsT, float* __restrict__ part, int nsplit) {
  __shared__ ushort Ah[128 * 64], Al[128 * 64];

  int bx  = blockIdx.x;
  int t   = threadIdx.x;
  int sp  = bx % nsplit;
  int rem = bx / nsplit;
  int it  = rem & 3;
  int s   = rem >> 2;
  int i0  = it * 64;
  int lchunk = L / nsplit;
  int l0     = sp * lchunk;
  int steps  = lchunk * 4;  // 4 jc-chunks of 64 per l

  int lane = t & 63, wn = t >> 6;
  int fr = lane & 15, q = lane >> 4;
  int rw = t >> 4, jq = (t & 15) * 4;  // A-staging: row 0..15, col-quad

  f32x4 acc[8];
#pragma unroll
  for (int mi = 0; mi < 8; ++mi) acc[mi] = (f32x4)0.f;

  // this lane's W row (i = i0 + wn*16 + fr), k-chunk q*8
  const size_t wlo = (size_t)(i0 + wn * 16 + fr) * D + q * 8;

  float4 rW[4];
  auto loadW = [&](int step) {
    if (step >= steps) step = steps - 1;
    int l  = l0 + (step >> 2);
    int jc = (step & 3) * 64;
    const float* wb = wp + ((size_t)l * NS + s) * (D * D) + wlo + jc;
    rW[0] = *(const float4*)(wb);
    rW[1] = *(const float4*)(wb + 4);
    rW[2] = *(const float4*)(wb + 32);
    rW[3] = *(const float4*)(wb + 36);
  };
  loadW(0);

  for (int step = 0; step < steps; ++step) {
    int l  = l0 + (step >> 2);
    int jc = (step & 3) * 64;
    // ---- stage A: A[b][k] = wls[b,l,s] * tf[b,l,jc+k], swizzled hi/lo ----
    const float* ab = tf + (size_t)l * D + jc + jq;
    const float* sb = wlsT + ((size_t)l * NS + s) * B;
#pragma unroll
    for (int p = 0; p < 8; ++p) {
      int bb = p * 16 + rw;
      float4 v = *(const float4*)(ab + (size_t)bb * (L * D));
      float sc = sb[bb];
      v.x *= sc; v.y *= sc; v.z *= sc; v.w *= sc;
      uint2 h, lo;
      split4(v, h, lo);
      *(uint2*)&Ah[swzA(bb, jq)] = h;
      *(uint2*)&Al[swzA(bb, jq)] = lo;
    }
    // ---- W fragments from prefetched regs (consume rW before reload) ----
    bf16x8 bh[2], bl[2];
#pragma unroll
    for (int k2 = 0; k2 < 2; ++k2) {
      uint2 h0, l0u, h1, l1u;
      split4(rW[k2 * 2], h0, l0u);
      split4(rW[k2 * 2 + 1], h1, l1u);
      uint4 hu = {h0.x, h0.y, h1.x, h1.y};
      uint4 lu = {l0u.x, l0u.y, l1u.x, l1u.y};
      bh[k2] = __builtin_bit_cast(bf16x8, hu);
      bl[k2] = __builtin_bit_cast(bf16x8, lu);
    }
    // ---- prefetch next step's W (in flight across barrier+MFMA) ----
    loadW(step + 1);
    LGKM_BARRIER();  // A visible; vmcnt NOT drained
    // ---- MFMA ----
#pragma unroll
    for (int k2 = 0; k2 < 2; ++k2) {
      int kb = k2 * 32 + q * 8;
#pragma unroll
      for (int mi = 0; mi < 8; ++mi) {
        bf16x8 ah = *(const bf16x8*)&Ah[swzA(mi * 16 + fr, kb)];
        bf16x8 al = *(const bf16x8*)&Al[swzA(mi * 16 + fr, kb)];
        acc[mi] = __builtin_amdgcn_mfma_f32_16x16x32_bf16(ah, bh[k2], acc[mi], 0, 0, 0);
        acc[mi] = __builtin_amdgcn_mfma_f32_16x16x32_bf16(ah, bl[k2], acc[mi], 0, 0, 0);
        acc[mi] = __builtin_amdgcn_mfma_f32_16x16x32_bf16(al, bh[k2], acc[mi], 0, 0, 0);
      }
    }
    LGKM_BARRIER();  // reads done before next stage overwrites
  }

  // ---- epilogue: write partials ----
  float* pout = part + ((size_t)sp * NS + s) * (B * D);
  int col = i0 + wn * 16 + fr;
#pragma unroll
  for (int mi = 0; mi < 8; ++mi)
#pragma unroll
    for (int r = 0; r < 4; ++r) {
      int bb = mi * 16 + q * 4 + r;
      pout[(size_t)bb * D + col] = acc[mi][r];
    }
}

// ---------------------------------------------------------------------------
// K3R: u_slots[b,s,i] = (sum_sp part[sp,s,b,i]) / weighted_c[b,s]
// ---------------------------------------------------------------------------
__global__ __launch_bounds__(256) void k3r_reduce(
    const float* __restrict__ part, const float* __restrict__ wc,
    float* __restrict__ u_slots, int nsplit) {
  int idx = blockIdx.x * 256 + threadIdx.x;  // over (s,b,i)
  int i  = idx & (D - 1);
  int sb = idx >> 8;
  int b  = sb & (B - 1);
  int s  = sb >> 7;
  float v = 0.f;
  for (int sp = 0; sp < nsplit; ++sp)
    v += part[(size_t)sp * (NS * B * D) + idx];
  u_slots[((size_t)b * NS + s) * D + i] = v / wc[b * NS + s];
}

// ---------------------------------------------------------------------------
// K4: per (b,s): logits2 = w_route_si[s] . u_slots[b,s]; softmax over NI;
//     w2 = c_si * a_slots.
// ---------------------------------------------------------------------------
__global__ __launch_bounds__(64) void k4_route_si(
    const float* __restrict__ u_slots, const float* __restrict__ wr_si,
    const float* __restrict__ a_slots, float* __restrict__ w2) {
  int bs = blockIdx.x;
  int s  = bs & (NS - 1);
  int lane = threadIdx.x;
  __shared__ float su[D];
  __shared__ float slog[NI];
#pragma unroll
  for (int jj = 0; jj < 4; ++jj) su[lane + jj * 64] = u_slots[bs * D + lane + jj * 64];
  __syncthreads();
  for (int i = 0; i < NI; ++i) {
    const float* w = wr_si + (s * NI + i) * D;
    float p = 0.f;
#pragma unroll
    for (int jj = 0; jj < 4; ++jj) {
      int j = lane + jj * 64;
      p = fmaf(w[j], su[j], p);
    }
    p = wave_reduce_sum(p);
    if (lane == 0) slog[i] = p;
  }
  __syncthreads();
  float v = (lane < NI) ? slog[lane] : -INFINITY;
  float m = wave_reduce_max(v);
  float e = (lane < NI) ? __expf(v - m) : 0.f;
  float ssum = wave_reduce_sum(e);
  if (lane < NI) w2[bs * NI + lane] = (e / ssum) * a_slots[bs];
}

// ---------------------------------------------------------------------------
// K5: wc2[b,i] = sum_s w2; a_intents = wc2 / sum_s a_slots.
// ---------------------------------------------------------------------------
__global__ __launch_bounds__(64) void k5_intents_agg(
    const float* __restrict__ w2, const float* __restrict__ a_slots,
    float* __restrict__ wc2, float* __restrict__ a_intents) {
  int b = blockIdx.x;
  int lane = threadIdx.x;
  float as = (lane < NS) ? a_slots[b * NS + lane] : 0.f;
  float sas = wave_reduce_sum(as);
  if (lane < NI) {
    float wc = 0.f;
    for (int s = 0; s < NS; ++s) wc += w2[(b * NS + s) * NI + lane];
    wc2[b * NI + lane] = wc;
    a_intents[b * NI + lane] = wc / sas;
  }
}

// ---------------------------------------------------------------------------
// K6: Wsum[s,i,k] = sum_j w_pose_si[s,i,j,k] (float4-vectorized over k).
// ---------------------------------------------------------------------------
__global__ __launch_bounds__(256) void k6_wsum(
    const float* __restrict__ wps, float* __restrict__ wsum) {
  __shared__ float red[4][D];
  int si = blockIdx.x;
  int t  = threadIdx.x;
  int k4 = (t & 63) * 4;
  int jg = t >> 6;
  const float* base = wps + (size_t)si * D * D;
  float4 acc = {0.f, 0.f, 0.f, 0.f};
  for (int j = jg; j < D; j += 4) {
    float4 v = *(const float4*)(base + (size_t)j * D + k4);
    acc.x += v.x; acc.y += v.y; acc.z += v.z; acc.w += v.w;
  }
  *(float4*)&red[jg][k4] = acc;
  __syncthreads();
  wsum[si * D + t] = (red[0][t] + red[1][t]) + (red[2][t] + red[3][t]);
}

// ---------------------------------------------------------------------------
// K7: u_intents[b,i,k] = sum_s w2[b,s,i]*u_slots[b,s,k]*Wsum[s,i,k] / wc2[b,i]
// ---------------------------------------------------------------------------
__global__ __launch_bounds__(256) void k7_uintents(
    const float* __restrict__ u_slots, const float* __restrict__ w2,
    const float* __restrict__ wsum, const float* __restrict__ wc2,
    float* __restrict__ u_intents) {
  int bi = blockIdx.x;
  int b = bi >> 4, i = bi & (NI - 1);
  int k = threadIdx.x;
  float acc = 0.f;
  for (int s = 0; s < NS; ++s) {
    float w = w2[(b * NS + s) * NI + i];
    acc = fmaf(w * u_slots[(b * NS + s) * D + k], wsum[(s * NI + i) * D + k], acc);
  }
  u_intents[bi * D + k] = acc / wc2[bi];
}

// ---------------------------------------------------------------------------
extern "C" void kernel_launch(void* const* d_in, const int* in_sizes, int n_in,
                              void* d_out, int out_size, void* d_ws, size_t ws_size,
                              hipStream_t stream) {
  const float* tf    = (const float*)d_in[0];  // (B,L,D)
  const float* wr_ws = (const float*)d_in[1];  // (L,NS,D)
  const float* wp_ws = (const float*)d_in[2];  // (L,NS,D,D)
  const float* wr_si = (const float*)d_in[3];  // (NS,NI,D)
  const float* wp_si = (const float*)d_in[4];  // (NS,NI,D,D)

  float* out       = (float*)d_out;
  float* a_slots   = out;                      // B*NS
  float* u_slots   = a_slots + B * NS;         // B*NS*D
  float* a_intents = u_slots + B * NS * D;     // B*NI
  float* u_intents = a_intents + B * NI;       // B*NI*D

  float* ws         = (float*)d_ws;
  float* wlsT       = ws;                      // L*NS*B  = 262144
  float* a_words    = wlsT + L * NS * B;       // B*L     = 8192
  float* weighted_c = a_words + B * L;         // B*NS    = 4096
  float* w2         = weighted_c + B * NS;     // B*NS*NI = 65536
  float* wc2        = w2 + B * NS * NI;        // B*NI    = 2048
  float* wsum       = wc2 + B * NI;            // NS*NI*D = 131072
  float* part       = wsum + NS * NI * D;      // nsplit * NS*B*D

  const size_t base_f  = 473088;
  const size_t chunk_f = (size_t)NS * B * D;   // 1,048,576 floats per split
  size_t avail_f = ws_size / sizeof(float);
  int nsplit = 1;
  if (avail_f >= base_f + 8 * chunk_f)      nsplit = 8;
  else if (avail_f >= base_f + 4 * chunk_f) nsplit = 4;
  else if (avail_f >= base_f + 2 * chunk_f) nsplit = 2;

  k1_route_words<<<B * L, 256, 0, stream>>>(tf, wr_ws, wlsT, a_words);
  k2_slots_agg<<<B, 64, 0, stream>>>(wlsT, a_words, weighted_c, a_slots);
  k3_mfma<<<128 * nsplit, 256, 0, stream>>>(tf, wp_ws, wlsT, part, nsplit);
  k3r_reduce<<<(NS * B * D) / 256, 256, 0, stream>>>(part, weighted_c, u_slots, nsplit);
  k6_wsum<<<NS * NI, 256, 0, stream>>>(wp_si, wsum);
  k4_route_si<<<B * NS, 64, 0, stream>>>(u_slots, wr_si, a_slots, w2);
  k5_intents_agg<<<B, 64, 0, stream>>>(w2, a_slots, wc2, a_intents);
  k7_uintents<<<B * NI, 256, 0, stream>>>(u_slots, w2, wsum, wc2, u_intents);
}